// Round 7
// baseline (155.387 us; speedup 1.0000x reference)
//
#include <hip/hip_runtime.h>
#include <cstddef>
#include <cstdint>

#define BB 8
#define SS 256
#define EE 256
#define NN1 16
#define NN2 16
#define DD 100
#define QQ 768

__device__ __forceinline__ float dot4(float4 a, float4 b) {
    return a.x * b.x + a.y * b.y + a.z * b.z + a.w * b.w;
}

// ---------------------------------------------------------------------------
// prep: blocks 0..15 -> per (b, layer) compute qk = 0.1 * Wk^T tanh(Wq q0 + bq)
//       blocks 16..23 -> per b inclusive scan of (input_ent != 0) -> rank (-1 = masked)
// ---------------------------------------------------------------------------
__global__ __launch_bounds__(256) void prep_kernel(
    const float* __restrict__ q, const int* __restrict__ ent,
    const float* __restrict__ Wq2, const float* __restrict__ bq2, const float* __restrict__ Wk2,
    const float* __restrict__ Wq1, const float* __restrict__ bq1, const float* __restrict__ Wk1,
    float* __restrict__ qk2o, float* __restrict__ qk1o, int* __restrict__ rk)
{
    const int blk = blockIdx.x, t = threadIdx.x;
    if (blk < 16) {
        const int b = blk >> 1, layer = blk & 1;
        const float* Wq = layer ? Wq1 : Wq2;
        const float* bq = layer ? bq1 : bq2;
        const float* Wk = layer ? Wk1 : Wk2;
        float* qko      = layer ? qk1o : qk2o;
        __shared__ float s_q[QQ];
        __shared__ float s_qi[DD];
        for (int i = t; i < QQ; i += 256) s_q[i] = q[(size_t)b * SS * QQ + i]; // q[b,0,:]
        __syncthreads();
        const float4* sq4 = (const float4*)s_q;
        const int r = t & 7;
        for (int d = t >> 3; d < DD; d += 32) {
            const float4* wq4 = (const float4*)(Wq + (size_t)d * QQ);
            float acc = 0.f;
            for (int c = r; c < QQ / 4; c += 8) acc += dot4(wq4[c], sq4[c]);
            acc += __shfl_xor(acc, 1, 8);
            acc += __shfl_xor(acc, 2, 8);
            acc += __shfl_xor(acc, 4, 8);
            if (r == 0) s_qi[d] = tanhf(acc + bq[d]);
        }
        __syncthreads();
        if (t < DD) {
            float acc = 0.f;
            for (int d = 0; d < DD; ++d) acc += s_qi[d] * Wk[d * DD + t]; // (Wk^T q_i)[t]
            qko[b * DD + t] = 0.1f * acc;   // fold 1/sqrt(100)
        }
    } else {
        const int b = blk - 16;
        __shared__ int s_m[SS];
        const int m = (ent[b * SS + t] != 0) ? 1 : 0;
        s_m[t] = m;
        __syncthreads();
        for (int off = 1; off < SS; off <<= 1) {
            const int add = (t >= off) ? s_m[t - off] : 0;
            __syncthreads();
            s_m[t] += add;
            __syncthreads();
        }
        int rank = s_m[t] - 1;
        rank = rank < 0 ? 0 : (rank > EE - 1 ? EE - 1 : rank);
        rk[b * SS + t] = m ? rank : -1;
    }
}

// ---------------------------------------------------------------------------
// dk2: single-wave blocks, batch-of-4 pipeline. Per batch:
//   issue K0..K3 (25.6 KB) -> [dots(a); softmax(a); issue V(a)] x4 -> PV x4.
// Tails of unit a run while K(a+1..3) and V(a..) are in flight: ~50 KB
// outstanding per wave through the whole tail region. qk in LDS so the
// in-order vmcnt queue holds only K/V stream loads.
// ---------------------------------------------------------------------------
__global__ __launch_bounds__(64) void dk2_kernel(
    const float* __restrict__ k2, const float* __restrict__ v2,
    const float* __restrict__ qk2g, float* __restrict__ c2o,
    int b0, int nb, int nunits)
{
    const int t = threadIdx.x;
    __shared__ float  s_part[1600];          // 4 units x 400 dot-partials
    __shared__ float4 s_pp[400];             // one unit's p*v, reused serially
    __shared__ float  s_qk[800];             // qk2 for up to 8 b's

    for (int i = t; i < nb * DD; i += 64) s_qk[i] = qk2g[b0 * DD + i];
    __syncthreads();                          // 1-wave: just a waitcnt
    const float4* sqk = (const float4*)s_qk;

    for (int u0 = blockIdx.x * 4; u0 < nunits; u0 += gridDim.x * 4) {
        const int brel = u0 >> 12;            // 4096 units per b; batch never spans b
        const float4* qk = sqk + brel * 25;
        const float4* kt = (const float4*)k2 + ((size_t)b0 * 4096 + u0) * 400;
        const float4* vt = (const float4*)v2 + ((size_t)b0 * 4096 + u0) * 400;

        float4 ka0[7], ka1[7], ka2[7], ka3[7];
        float4 va0[7], va1[7], va2[7], va3[7];
        float p0, p1, p2, p3;

#define LDX(A, PTR, base)                                                     \
        { _Pragma("unroll") for (int j = 0; j < 6; ++j) A[j] = (PTR)[(base) + t + 64*j]; \
          if (t < 16) A[6] = (PTR)[(base) + 384 + t]; }

#define DOTS(A, po)                                                           \
        { _Pragma("unroll") for (int j = 0; j < 6; ++j) { const int i = t + 64*j; \
              s_part[(po) + i] = dot4(A[j], qk[i % 25]); }                    \
          if (t < 16) { const int i = 384 + t; s_part[(po) + i] = dot4(A[6], qk[i % 25]); } }

#define SMAX(P, po)                                                           \
        { float lg = 0.f;                                                     \
          if (t < 16) {                                                       \
              _Pragma("unroll") for (int c = 0; c < 25; ++c) lg += s_part[(po) + t * 25 + c]; \
              if (lg == 0.0f) lg = -10000.0f;                                 \
              lg = lg >= 0.f ? lg : 0.01f * lg;                               \
          }                                                                   \
          float mx = lg;                                                      \
          mx = fmaxf(mx, __shfl_xor(mx, 1, 16));                              \
          mx = fmaxf(mx, __shfl_xor(mx, 2, 16));                              \
          mx = fmaxf(mx, __shfl_xor(mx, 4, 16));                              \
          mx = fmaxf(mx, __shfl_xor(mx, 8, 16));                              \
          const float e = __expf(lg - mx);                                    \
          float sm = e;                                                       \
          sm += __shfl_xor(sm, 1, 16);                                        \
          sm += __shfl_xor(sm, 2, 16);                                        \
          sm += __shfl_xor(sm, 4, 16);                                        \
          sm += __shfl_xor(sm, 8, 16);                                        \
          P = e / sm;                                                         \
          if (P == 0.0625f) P = 0.f; }

#define PV(A, P, uu)                                                          \
        { _Pragma("unroll") for (int j = 0; j < 6; ++j) { const int i = t + 64*j; \
              const float pn = __shfl(P, i / 25, 64);                         \
              s_pp[i] = make_float4(pn*A[j].x, pn*A[j].y, pn*A[j].z, pn*A[j].w); } \
          if (t < 16) { const int i = 384 + t;                                \
              const float pn = __shfl(P, 15, 64);                             \
              s_pp[i] = make_float4(pn*A[6].x, pn*A[6].y, pn*A[6].z, pn*A[6].w); } \
          __syncthreads();                                                    \
          if (t < 25) { float4 a = make_float4(0.f,0.f,0.f,0.f);              \
              _Pragma("unroll") for (int n = 0; n < 16; ++n) {                \
                  const float4 x = s_pp[n * 25 + t];                          \
                  a.x += x.x; a.y += x.y; a.z += x.z; a.w += x.w; }           \
              ((float4*)c2o)[(size_t)(uu) * 25 + t] = a; }                    \
          __syncthreads(); }

        // issue all K
        LDX(ka0, kt, 0) LDX(ka1, kt, 400) LDX(ka2, kt, 800) LDX(ka3, kt, 1200)
        // tails A interleaved with V issues (K/V stay in flight throughout)
        DOTS(ka0, 0)     LDX(va0, vt, 0)     SMAX(p0, 0)
        DOTS(ka1, 400)   LDX(va1, vt, 400)   SMAX(p1, 400)
        DOTS(ka2, 800)   LDX(va2, vt, 800)   SMAX(p2, 800)
        DOTS(ka3, 1200)  LDX(va3, vt, 1200)  SMAX(p3, 1200)
        // tails B
        PV(va0, p0, u0) PV(va1, p1, u0 + 1) PV(va2, p2, u0 + 2) PV(va3, p3, u0 + 3)

#undef LDX
#undef DOTS
#undef SMAX
#undef PV
    }
}

// ---------------------------------------------------------------------------
// dk1: single-wave blocks, 2 per (bb,e): half 0 emits v1 part (d 0..99),
// half 1 emits c2 part (d 100..199). Both redundantly compute p.
// ---------------------------------------------------------------------------
__global__ __launch_bounds__(64) void dk1_kernel(
    const float* __restrict__ k1, const float* __restrict__ v1,
    const float* __restrict__ c2i, const float* __restrict__ qk1g,
    float* __restrict__ comb, int b0)
{
    const int blk  = blockIdx.x;
    const int bbe  = blk >> 1;           // chunk-local (bb,e)
    const int half = blk & 1;
    const int b    = b0 + (bbe >> 8);
    const int be   = (b << 8) | (bbe & 255);
    const int t    = threadIdx.x;

    __shared__ float4 s_pp[400];
    float* s_part = (float*)s_pp;

    const float4* kt = (const float4*)k1 + (size_t)be * 400;
    const float4* vt = half ? (const float4*)c2i + (size_t)bbe * 400
                            : (const float4*)v1 + (size_t)be * 400;
    const float4* qk = (const float4*)qk1g + b * 25;

    float4 ka[7], va[7];
    #pragma unroll
    for (int j = 0; j < 6; ++j) { ka[j] = kt[t + 64 * j]; va[j] = vt[t + 64 * j]; }
    if (t < 16) { ka[6] = kt[384 + t]; va[6] = vt[384 + t]; }

    #pragma unroll
    for (int j = 0; j < 6; ++j) {
        const int i = t + 64 * j;
        s_part[i] = dot4(ka[j], qk[i % 25]);
    }
    if (t < 16) { const int i = 384 + t; s_part[i] = dot4(ka[6], qk[i % 25]); }
    __syncthreads();

    float p = 0.f;
    {
        float lg = 0.f;
        if (t < 16) {
            #pragma unroll
            for (int c = 0; c < 25; ++c) lg += s_part[t * 25 + c];
            if (lg == 0.0f) lg = -10000.0f;
            lg = lg >= 0.f ? lg : 0.01f * lg;
        }
        float mx = lg;
        mx = fmaxf(mx, __shfl_xor(mx, 1, 16));
        mx = fmaxf(mx, __shfl_xor(mx, 2, 16));
        mx = fmaxf(mx, __shfl_xor(mx, 4, 16));
        mx = fmaxf(mx, __shfl_xor(mx, 8, 16));
        const float e = __expf(lg - mx);
        float sm = e;
        sm += __shfl_xor(sm, 1, 16);
        sm += __shfl_xor(sm, 2, 16);
        sm += __shfl_xor(sm, 4, 16);
        sm += __shfl_xor(sm, 8, 16);
        p = e / sm;
        if (p == 0.0625f) p = 0.f;
    }
    __syncthreads();

    #pragma unroll
    for (int j = 0; j < 6; ++j) {
        const int i = t + 64 * j;
        const float pn = __shfl(p, i / 25, 64);
        s_pp[i] = make_float4(pn * va[j].x, pn * va[j].y, pn * va[j].z, pn * va[j].w);
    }
    if (t < 16) {
        const int i = 384 + t;
        const float pn = __shfl(p, 15, 64);
        s_pp[i] = make_float4(pn * va[6].x, pn * va[6].y, pn * va[6].z, pn * va[6].w);
    }
    __syncthreads();

    if (t < 25) {
        float4 a = make_float4(0.f, 0.f, 0.f, 0.f);
        #pragma unroll
        for (int n = 0; n < 16; ++n) {
            const float4 x = s_pp[n * 25 + t];
            a.x += x.x; a.y += x.y; a.z += x.z; a.w += x.w;
        }
        ((float4*)comb)[(size_t)be * 50 + half * 25 + t] = a;
    }
}

// ---------------------------------------------------------------------------
// gather: one block per (b,s)
// ---------------------------------------------------------------------------
__global__ __launch_bounds__(64) void gather_kernel(
    const float* __restrict__ comb, const int* __restrict__ rk, float* __restrict__ out)
{
    const int bs = blockIdx.x;
    const int b  = bs >> 8;
    const int t  = threadIdx.x;
    const int r  = rk[bs];
    float* o = out + (size_t)bs * (2 * DD);
    if (r < 0) {
        for (int d = t; d < 2 * DD; d += 64) o[d] = 0.f;
    } else {
        const float* src = comb + (size_t)(b * EE + r) * (2 * DD);
        for (int d = t; d < 2 * DD; d += 64) o[d] = src[d];
    }
}

extern "C" void kernel_launch(void* const* d_in, const int* in_sizes, int n_in,
                              void* d_out, int out_size, void* d_ws, size_t ws_size,
                              hipStream_t stream)
{
    const int*   ent = (const int*)d_in[0];
    const float* q   = (const float*)d_in[1];
    const float* k1  = (const float*)d_in[2];
    const float* v1  = (const float*)d_in[3];
    const float* k2  = (const float*)d_in[4];
    const float* v2  = (const float*)d_in[5];
    const float* Wq2 = (const float*)d_in[6];
    const float* bq2 = (const float*)d_in[7];
    const float* Wk2 = (const float*)d_in[8];
    const float* Wq1 = (const float*)d_in[9];
    const float* bq1 = (const float*)d_in[10];
    const float* Wk1 = (const float*)d_in[11];
    float* out = (float*)d_out;

    float* ws   = (float*)d_ws;
    float* qk2  = ws;                          // [0, 1024)
    float* qk1  = ws + 1024;                   // [1024, 2048)
    int*   rk   = (int*)(ws + 2048);           // [2048, 4096) as ints
    float* comb = ws + 4096;                   // [4096, 4096+409600)
    float* c2   = ws + 4096 + 409600;          // per-b chunks of 409600 floats

    const size_t fixed = 4096 + 409600;        // floats
    const size_t perb  = (size_t)EE * NN1 * DD; // 409600 floats per batch
    size_t wsf = ws_size / sizeof(float);
    int kb = (wsf > fixed) ? (int)((wsf - fixed) / perb) : 1;
    if (kb < 1) kb = 1;
    if (kb > BB) kb = BB;

    prep_kernel<<<24, 256, 0, stream>>>(q, ent, Wq2, bq2, Wk2, Wq1, bq1, Wk1, qk2, qk1, rk);
    for (int b0 = 0; b0 < BB; b0 += kb) {
        const int nb = (BB - b0 < kb) ? (BB - b0) : kb;
        const int nunits = nb * EE * NN1;      // single-tile units
        int grid = (nunits + 3) / 4;
        if (grid > 3072) grid = 3072;
        dk2_kernel<<<grid, 64, 0, stream>>>(k2, v2, qk2, c2, b0, nb, nunits);
        dk1_kernel<<<nb * EE * 2, 64, 0, stream>>>(k1, v1, c2, qk1, comb, b0);
    }
    gather_kernel<<<BB * SS, 64, 0, stream>>>(comb, rk, out);
}